// Round 1
// baseline (433.782 us; speedup 1.0000x reference)
//
#include <hip/hip_runtime.h>
#include <hip/hip_bf16.h>
#include <math.h>

typedef short short8 __attribute__((ext_vector_type(8)));
typedef float floatx4 __attribute__((ext_vector_type(4)));

#define D 128
#define Q 2500
#define QPAD 2560
#define NK 10080
#define NKPAD 10112
// 1/sqrt(32) * log2(e)
#define QSCALE 0.25501268426834347f
#define NEGBIG -3.0e38f

__device__ __forceinline__ unsigned short f2bf(float f) {
    unsigned u = __float_as_uint(f);
    unsigned r = (u + 0x7fffu + ((u >> 16) & 1u)) >> 16;
    return (unsigned short)r;
}

// ---------------- LayerNorm kernel: one wave per position ----------------
__global__ void ln_kernel(const float* __restrict__ qi, const float* __restrict__ ki,
                          const float* __restrict__ vi,
                          const float* __restrict__ qw, const float* __restrict__ qb,
                          const float* __restrict__ kw, const float* __restrict__ kb,
                          const float* __restrict__ vw, const float* __restrict__ vb,
                          unsigned short* __restrict__ xq, unsigned short* __restrict__ xk,
                          unsigned short* __restrict__ xv) {
    int job = blockIdx.x * 4 + (threadIdx.x >> 6);
    int lane = threadIdx.x & 63;
    const float *g, *b, *a0, *a1;
    unsigned short* dst;
    if (job < Q) {
        int p = job;
        a0 = qi + lane * Q + p; a1 = qi + (lane + 64) * Q + p;
        g = qw; b = qb; dst = xq + p * D;
    } else if (job < Q + NK) {
        int p = job - Q;
        int n = p / 1680; int r = p - n * 1680;
        const float* base = ki + (n * 128) * 1680 + r;
        a0 = base + lane * 1680; a1 = base + (lane + 64) * 1680;
        g = kw; b = kb; dst = xk + p * D;
    } else {
        int p = job - (Q + NK);
        int n = p / 1680; int r = p - n * 1680;
        const float* base = vi + (n * 128) * 1680 + r;
        a0 = base + lane * 1680; a1 = base + (lane + 64) * 1680;
        g = vw; b = vb; dst = xv + p * D;
    }
    float x0 = *a0, x1 = *a1;
    float s = x0 + x1, ss = x0 * x0 + x1 * x1;
    #pragma unroll
    for (int m = 1; m <= 32; m <<= 1) {
        s += __shfl_xor(s, m, 64);
        ss += __shfl_xor(ss, m, 64);
    }
    float mean = s * (1.0f / 128.0f);
    float var = ss * (1.0f / 128.0f) - mean * mean;
    float rstd = rsqrtf(var + 1e-5f);
    dst[lane] = f2bf((x0 - mean) * rstd * g[lane] + b[lane]);
    dst[lane + 64] = f2bf((x1 - mean) * rstd * g[lane + 64] + b[lane + 64]);
}

// ---------------- Projection GEMM (q/k/v), MFMA bf16 ----------------
__global__ __launch_bounds__(256) void proj_kernel(
    const unsigned short* __restrict__ xq, const unsigned short* __restrict__ xk,
    const unsigned short* __restrict__ xv,
    const float* __restrict__ wq, const float* __restrict__ bq,
    const float* __restrict__ wk, const float* __restrict__ bk,
    const float* __restrict__ wv, const float* __restrict__ bv,
    unsigned short* __restrict__ qh, unsigned short* __restrict__ kh,
    unsigned short* __restrict__ vh) {
    int bid = blockIdx.x;
    const unsigned short* src; const float *w, *bias; unsigned short* dst; float scale; int mb;
    if (bid < 40)       { src = xq; w = wq; bias = bq; dst = qh; scale = QSCALE; mb = bid * 64; }
    else if (bid < 198) { src = xk; w = wk; bias = bk; dst = kh; scale = 1.0f;  mb = (bid - 40) * 64; }
    else                { src = xv; w = wv; bias = bv; dst = vh; scale = 1.0f;  mb = (bid - 198) * 64; }
    int wave = threadIdx.x >> 6, lane = threadIdx.x & 63;
    int l15 = lane & 15, quad = lane >> 4;
    int m0 = mb + wave * 16;
    floatx4 acc[8];
    #pragma unroll
    for (int i = 0; i < 8; i++) acc[i] = (floatx4){0.f, 0.f, 0.f, 0.f};
    #pragma unroll
    for (int kf = 0; kf < 4; kf++) {
        short8 A = *(const short8*)(src + (m0 + l15) * D + kf * 32 + quad * 8);
        #pragma unroll
        for (int nt = 0; nt < 8; nt++) {
            short8 B;
            #pragma unroll
            for (int j = 0; j < 8; j++)
                B[j] = (short)f2bf(w[(kf * 32 + quad * 8 + j) * D + nt * 16 + l15]);
            acc[nt] = __builtin_amdgcn_mfma_f32_16x16x32_bf16(A, B, acc[nt], 0, 0, 0);
        }
    }
    #pragma unroll
    for (int nt = 0; nt < 8; nt++) {
        float bb = bias[nt * 16 + l15];
        #pragma unroll
        for (int r = 0; r < 4; r++)
            dst[(m0 + quad * 4 + r) * D + nt * 16 + l15] = f2bf((acc[nt][r] + bb) * scale);
    }
}

// ---------------- Fused attention: TQ=32, 8 NK-splits, wave=head ----------------
__global__ __launch_bounds__(256) void attn_kernel(
    const unsigned short* __restrict__ qh, const unsigned short* __restrict__ kh,
    const unsigned short* __restrict__ vh,
    const float* __restrict__ Wl, const int* __restrict__ vis,
    float* __restrict__ Opart, float* __restrict__ lpart) {
    __shared__ short plds[4 * 2 * 16 * 40];  // per-wave [2 sub][16 q][40 k-pad] bf16
    int bid = blockIdx.x;
    int split = bid & 7, qt = bid >> 3;
    int h = threadIdx.x >> 6, lane = threadIdx.x & 63;
    int l15 = lane & 15, quad = lane >> 4;
    int qb = qt * 32;
    int kb0 = split * 1280;
    int nch = (split == 7) ? 35 : 40;
    short* pw = plds + h * 1280;

    short8 qA[2];
    #pragma unroll
    for (int s = 0; s < 2; s++)
        qA[s] = *(const short8*)(qh + (qb + s * 16 + l15) * D + h * 32 + quad * 8);

    const float* wrow[8]; const int* vrow[8];
    #pragma unroll
    for (int s = 0; s < 2; s++)
        #pragma unroll
        for (int r = 0; r < 4; r++) {
            int row = qb + s * 16 + quad * 4 + r;
            row = row < Q ? row : (Q - 1);
            wrow[s * 4 + r] = Wl + (size_t)row * NK;
            vrow[s * 4 + r] = vis + (size_t)row * NK;
        }

    const floatx4 zf = {0.f, 0.f, 0.f, 0.f};
    floatx4 O[2][2];
    float lacc[2][4];
    #pragma unroll
    for (int s = 0; s < 2; s++)
        #pragma unroll
        for (int i = 0; i < 4; i++) { lacc[s][i] = 0.f; }
    O[0][0] = zf; O[0][1] = zf; O[1][0] = zf; O[1][1] = zf;

    for (int c = 0; c < nch; c++) {
        int kb = kb0 + c * 32;
        short8 kB0 = *(const short8*)(kh + (kb + l15) * D + h * 32 + quad * 8);
        short8 kB1 = *(const short8*)(kh + (kb + 16 + l15) * D + h * 32 + quad * 8);
        short8 vB0, vB1;
        #pragma unroll
        for (int j = 0; j < 8; j++) {
            int kk = kb + quad * 8 + j;
            vB0[j] = (short)vh[kk * D + h * 32 + l15];
            vB1[j] = (short)vh[kk * D + h * 32 + 16 + l15];
        }
        #pragma unroll
        for (int s = 0; s < 2; s++) {
            floatx4 S0 = __builtin_amdgcn_mfma_f32_16x16x32_bf16(qA[s], kB0, zf, 0, 0, 0);
            floatx4 S1 = __builtin_amdgcn_mfma_f32_16x16x32_bf16(qA[s], kB1, zf, 0, 0, 0);
            #pragma unroll
            for (int r = 0; r < 4; r++) {
                const float* wr = wrow[s * 4 + r];
                const int* vr = vrow[s * 4 + r];
                float w0 = wr[kb + l15], w1 = wr[kb + 16 + l15];
                int v0 = vr[kb + l15], v1 = vr[kb + 16 + l15];
                float L0 = (v0 ? S0[r] : NEGBIG) * w0;  // logits pre-scaled by log2e via QSCALE
                float L1 = (v1 ? S1[r] : NEGBIG) * w1;
                float p0 = exp2f(L0), p1 = exp2f(L1);
                lacc[s][r] += p0 + p1;
                pw[s * 640 + (quad * 4 + r) * 40 + l15] = (short)f2bf(p0);
                pw[s * 640 + (quad * 4 + r) * 40 + 16 + l15] = (short)f2bf(p1);
            }
        }
        #pragma unroll
        for (int s = 0; s < 2; s++) {
            short8 P = *(const short8*)(pw + s * 640 + l15 * 40 + quad * 8);
            O[s][0] = __builtin_amdgcn_mfma_f32_16x16x32_bf16(P, vB0, O[s][0], 0, 0, 0);
            O[s][1] = __builtin_amdgcn_mfma_f32_16x16x32_bf16(P, vB1, O[s][1], 0, 0, 0);
        }
    }

    #pragma unroll
    for (int s = 0; s < 2; s++)
        #pragma unroll
        for (int r = 0; r < 4; r++) {
            float lv = lacc[s][r];
            lv += __shfl_xor(lv, 1, 64);
            lv += __shfl_xor(lv, 2, 64);
            lv += __shfl_xor(lv, 4, 64);
            lv += __shfl_xor(lv, 8, 64);
            int row = qb + s * 16 + quad * 4 + r;
            if (l15 == 0) lpart[(split * QPAD + row) * 4 + h] = lv;
            float* op = Opart + ((size_t)(split * QPAD + row) * 4 + h) * 32;
            op[l15] = O[s][0][r];
            op[16 + l15] = O[s][1][r];
        }
}

// ---------------- Epilogue: combine + wp + skip + preLN + MLP + postLN ----------------
__global__ __launch_bounds__(256) void epi_kernel(
    const float* __restrict__ Opart, const float* __restrict__ lpart,
    const float* __restrict__ wp, const float* __restrict__ bp,
    const float* __restrict__ skip,
    const float* __restrict__ pre_w, const float* __restrict__ pre_b,
    const float* __restrict__ w1, const float* __restrict__ b1,
    const float* __restrict__ w2, const float* __restrict__ b2,
    const float* __restrict__ post_w, const float* __restrict__ post_b,
    float* __restrict__ out) {
    __shared__ __align__(16) char smem[68608];
    short* A1 = (short*)smem;              // [64][136] bf16
    short* Z1 = (short*)(smem + 17408);    // [64][136] bf16
    short* H1 = (short*)(smem + 34816);    // [64][264] bf16
    float* Zout = (float*)smem;            // [128][65] f32 (overlays A1+Z1, used after barrier)

    int qb = blockIdx.x * 64;
    int t = threadIdx.x;
    int wave = t >> 6, lane = t & 63;
    int l15 = lane & 15, quad = lane >> 4;
    int m0 = wave * 16;

    // --- combine splits: thread t -> (row pl = t>>2, head hh = t&3); wave-private rows ---
    {
        int pl = t >> 2, hh = t & 3;
        int q = qb + pl;
        if (q < Q) {
            float ltot = 0.f;
            #pragma unroll
            for (int s = 0; s < 8; s++) ltot += lpart[(s * QPAD + q) * 4 + hh];
            float inv = 1.0f / fmaxf(ltot, 1e-30f);
            floatx4 acc4[8];
            #pragma unroll
            for (int i = 0; i < 8; i++) acc4[i] = (floatx4){0.f, 0.f, 0.f, 0.f};
            #pragma unroll
            for (int s = 0; s < 8; s++) {
                const floatx4* op = (const floatx4*)(Opart + ((size_t)(s * QPAD + q) * 4 + hh) * 32);
                #pragma unroll
                for (int i = 0; i < 8; i++) acc4[i] += op[i];
            }
            #pragma unroll
            for (int i = 0; i < 8; i++)
                #pragma unroll
                for (int j = 0; j < 4; j++)
                    A1[pl * 136 + hh * 32 + i * 4 + j] = (short)f2bf(acc4[i][j] * inv);
        } else {
            #pragma unroll
            for (int d = 0; d < 32; d++) A1[pl * 136 + hh * 32 + d] = 0;
        }
    }

    // --- G1: Z = A1 @ wp + bp + skip ---
    floatx4 z[8];
    #pragma unroll
    for (int i = 0; i < 8; i++) z[i] = (floatx4){0.f, 0.f, 0.f, 0.f};
    #pragma unroll
    for (int kf = 0; kf < 4; kf++) {
        short8 A = *(const short8*)(A1 + (m0 + l15) * 136 + kf * 32 + quad * 8);
        #pragma unroll
        for (int nt = 0; nt < 8; nt++) {
            short8 B;
            #pragma unroll
            for (int j = 0; j < 8; j++)
                B[j] = (short)f2bf(wp[(kf * 32 + quad * 8 + j) * D + nt * 16 + l15]);
            z[nt] = __builtin_amdgcn_mfma_f32_16x16x32_bf16(A, B, z[nt], 0, 0, 0);
        }
    }
    float Zv[8][4];
    #pragma unroll
    for (int nt = 0; nt < 8; nt++) {
        int n = nt * 16 + l15;
        float bb = bp[n];
        #pragma unroll
        for (int r = 0; r < 4; r++) {
            int q = qb + m0 + quad * 4 + r;
            int qc = q < Q ? q : (Q - 1);
            Zv[nt][r] = z[nt][r] + bb + skip[n * Q + qc];
        }
    }
    // --- pre-LN ---
    float Zn[8][4];
    {
        #pragma unroll
        for (int r = 0; r < 4; r++) {
            float s1 = 0.f, s2 = 0.f;
            #pragma unroll
            for (int nt = 0; nt < 8; nt++) { s1 += Zv[nt][r]; s2 += Zv[nt][r] * Zv[nt][r]; }
            s1 += __shfl_xor(s1, 1, 64); s2 += __shfl_xor(s2, 1, 64);
            s1 += __shfl_xor(s1, 2, 64); s2 += __shfl_xor(s2, 2, 64);
            s1 += __shfl_xor(s1, 4, 64); s2 += __shfl_xor(s2, 4, 64);
            s1 += __shfl_xor(s1, 8, 64); s2 += __shfl_xor(s2, 8, 64);
            float mean = s1 * (1.0f / 128.0f);
            float var = s2 * (1.0f / 128.0f) - mean * mean;
            float rstd = rsqrtf(var + 1e-5f);
            #pragma unroll
            for (int nt = 0; nt < 8; nt++) Zn[nt][r] = (Zv[nt][r] - mean) * rstd;
        }
        #pragma unroll
        for (int nt = 0; nt < 8; nt++) {
            int n = nt * 16 + l15;
            float g = pre_w[n], be = pre_b[n];
            #pragma unroll
            for (int r = 0; r < 4; r++) {
                Zn[nt][r] = Zn[nt][r] * g + be;
                Z1[(m0 + quad * 4 + r) * 136 + n] = (short)f2bf(Zn[nt][r]);
            }
        }
    }
    // --- G2: H = gelu(Z1 @ w1 + b1) ---
    {
        floatx4 h2[16];
        #pragma unroll
        for (int i = 0; i < 16; i++) h2[i] = (floatx4){0.f, 0.f, 0.f, 0.f};
        #pragma unroll
        for (int kf = 0; kf < 4; kf++) {
            short8 A = *(const short8*)(Z1 + (m0 + l15) * 136 + kf * 32 + quad * 8);
            #pragma unroll
            for (int nt = 0; nt < 16; nt++) {
                short8 B;
                #pragma unroll
                for (int j = 0; j < 8; j++)
                    B[j] = (short)f2bf(w1[(kf * 32 + quad * 8 + j) * 256 + nt * 16 + l15]);
                h2[nt] = __builtin_amdgcn_mfma_f32_16x16x32_bf16(A, B, h2[nt], 0, 0, 0);
            }
        }
        #pragma unroll
        for (int nt = 0; nt < 16; nt++) {
            int n = nt * 16 + l15;
            float bb = b1[n];
            #pragma unroll
            for (int r = 0; r < 4; r++) {
                float x = h2[nt][r] + bb;
                float gl = 0.5f * x * (1.0f + erff(x * 0.70710678118654752f));
                H1[(m0 + quad * 4 + r) * 264 + n] = (short)f2bf(gl);
            }
        }
    }
    // --- G3: R = H1 @ w2 + b2; z2 = Zn + R ---
    floatx4 o3[8];
    #pragma unroll
    for (int i = 0; i < 8; i++) o3[i] = (floatx4){0.f, 0.f, 0.f, 0.f};
    #pragma unroll
    for (int kf = 0; kf < 8; kf++) {
        short8 A = *(const short8*)(H1 + (m0 + l15) * 264 + kf * 32 + quad * 8);
        #pragma unroll
        for (int nt = 0; nt < 8; nt++) {
            short8 B;
            #pragma unroll
            for (int j = 0; j < 8; j++)
                B[j] = (short)f2bf(w2[(kf * 32 + quad * 8 + j) * D + nt * 16 + l15]);
            o3[nt] = __builtin_amdgcn_mfma_f32_16x16x32_bf16(A, B, o3[nt], 0, 0, 0);
        }
    }
    float Z2[8][4];
    #pragma unroll
    for (int nt = 0; nt < 8; nt++) {
        int n = nt * 16 + l15;
        float bb = b2[n];
        #pragma unroll
        for (int r = 0; r < 4; r++) Z2[nt][r] = Zn[nt][r] + o3[nt][r] + bb;
    }
    // --- post-LN ---
    float Zo[8][4];
    {
        #pragma unroll
        for (int r = 0; r < 4; r++) {
            float s1 = 0.f, s2 = 0.f;
            #pragma unroll
            for (int nt = 0; nt < 8; nt++) { s1 += Z2[nt][r]; s2 += Z2[nt][r] * Z2[nt][r]; }
            s1 += __shfl_xor(s1, 1, 64); s2 += __shfl_xor(s2, 1, 64);
            s1 += __shfl_xor(s1, 2, 64); s2 += __shfl_xor(s2, 2, 64);
            s1 += __shfl_xor(s1, 4, 64); s2 += __shfl_xor(s2, 4, 64);
            s1 += __shfl_xor(s1, 8, 64); s2 += __shfl_xor(s2, 8, 64);
            float mean = s1 * (1.0f / 128.0f);
            float var = s2 * (1.0f / 128.0f) - mean * mean;
            float rstd = rsqrtf(var + 1e-5f);
            #pragma unroll
            for (int nt = 0; nt < 8; nt++) Zo[nt][r] = (Z2[nt][r] - mean) * rstd;
        }
        #pragma unroll
        for (int nt = 0; nt < 8; nt++) {
            int n = nt * 16 + l15;
            float g = post_w[n], be = post_b[n];
            #pragma unroll
            for (int r = 0; r < 4; r++) Zo[nt][r] = Zo[nt][r] * g + be;
        }
    }
    // --- transposed store via LDS (Zout overlays A1/Z1: barrier first) ---
    __syncthreads();
    #pragma unroll
    for (int nt = 0; nt < 8; nt++)
        #pragma unroll
        for (int r = 0; r < 4; r++)
            Zout[(nt * 16 + l15) * 65 + m0 + quad * 4 + r] = Zo[nt][r];
    __syncthreads();
    {
        int pl = t & 63;
        int q = qb + pl;
        if (q < Q) {
            #pragma unroll
            for (int it = 0; it < 32; it++) {
                int n = it * 4 + (t >> 6);
                out[n * Q + q] = Zout[n * 65 + pl];
            }
        }
    }
}

extern "C" void kernel_launch(void* const* d_in, const int* in_sizes, int n_in,
                              void* d_out, int out_size, void* d_ws, size_t ws_size,
                              hipStream_t stream) {
    (void)in_sizes; (void)n_in; (void)out_size; (void)ws_size;
    const float* q      = (const float*)d_in[0];
    const float* k      = (const float*)d_in[1];
    const float* v      = (const float*)d_in[2];
    const float* Wl     = (const float*)d_in[3];
    const int*   vis    = (const int*)  d_in[4];
    const float* skip   = (const float*)d_in[5];
    const float* qn_w   = (const float*)d_in[6];
    const float* qn_b   = (const float*)d_in[7];
    const float* kn_w   = (const float*)d_in[8];
    const float* kn_b   = (const float*)d_in[9];
    const float* vn_w   = (const float*)d_in[10];
    const float* vn_b   = (const float*)d_in[11];
    const float* pre_w  = (const float*)d_in[12];
    const float* pre_b  = (const float*)d_in[13];
    const float* post_w = (const float*)d_in[14];
    const float* post_b = (const float*)d_in[15];
    const float* wq     = (const float*)d_in[16];
    const float* bq     = (const float*)d_in[17];
    const float* wk     = (const float*)d_in[18];
    const float* bk     = (const float*)d_in[19];
    const float* wv     = (const float*)d_in[20];
    const float* bv     = (const float*)d_in[21];
    const float* wp     = (const float*)d_in[22];
    const float* bp     = (const float*)d_in[23];
    const float* w1     = (const float*)d_in[24];
    const float* b1     = (const float*)d_in[25];
    const float* w2     = (const float*)d_in[26];
    const float* b2     = (const float*)d_in[27];
    float* out = (float*)d_out;

    char* ws = (char*)d_ws;
    unsigned short* xq = (unsigned short*)(ws + 0);         //  2560*128 bf16
    unsigned short* xk = (unsigned short*)(ws + 655360);    // 10112*128 bf16
    unsigned short* xv = (unsigned short*)(ws + 3244032);   // 10112*128 bf16
    unsigned short* qh = (unsigned short*)(ws + 5832704);   //  2560*128 bf16
    unsigned short* kh = (unsigned short*)(ws + 6488064);   // 10112*128 bf16
    unsigned short* vh = (unsigned short*)(ws + 9076736);   // 10112*128 bf16
    float* Opart = (float*)(ws + 11665408);                 // 8*2560*4*32 f32
    float* lpart = (float*)(ws + 22151168);                 // 8*2560*4 f32
    // total ws used: 22478848 bytes

    ln_kernel<<<dim3(5665), dim3(256), 0, stream>>>(q, k, v, qn_w, qn_b, kn_w, kn_b, vn_w, vn_b,
                                                    xq, xk, xv);
    proj_kernel<<<dim3(356), dim3(256), 0, stream>>>(xq, xk, xv, wq, bq, wk, bk, wv, bv,
                                                     qh, kh, vh);
    attn_kernel<<<dim3(632), dim3(256), 0, stream>>>(qh, kh, vh, Wl, vis, Opart, lpart);
    epi_kernel<<<dim3(40), dim3(256), 0, stream>>>(Opart, lpart, wp, bp, skip,
                                                   pre_w, pre_b, w1, b1, w2, b2,
                                                   post_w, post_b, out);
}

// Round 2
// 426.075 us; speedup vs baseline: 1.0181x; 1.0181x over previous
//
#include <hip/hip_runtime.h>
#include <hip/hip_bf16.h>
#include <math.h>

typedef short short8 __attribute__((ext_vector_type(8)));
typedef float floatx4 __attribute__((ext_vector_type(4)));

#define D 128
#define Q 2500
#define QPAD 2560
#define NK 10080
#define NKPAD 10112
#define SPLITS 35
#define CPS 9  // chunks of 32 k per split; 35*9*32 = 10080
// 1/sqrt(32) * log2(e)
#define QSCALE 0.25501268426834347f
#define NEGBIG -3.0e38f

__device__ __forceinline__ unsigned short f2bf(float f) {
    unsigned u = __float_as_uint(f);
    unsigned r = (u + 0x7fffu + ((u >> 16) & 1u)) >> 16;
    return (unsigned short)r;
}
// pack two floats to bf16 pair (lo,hi) with round-half-away
__device__ __forceinline__ unsigned pack2bf(float lo, float hi) {
    unsigned u0 = __float_as_uint(lo) + 0x8000u;
    unsigned u1 = __float_as_uint(hi) + 0x8000u;
    return (u0 >> 16) | (u1 & 0xffff0000u);
}
__device__ __forceinline__ float bflo(unsigned u) { return __uint_as_float(u << 16); }
__device__ __forceinline__ float bfhi(unsigned u) { return __uint_as_float(u & 0xffff0000u); }

// ---------- weight convert: fp32 [in][out] -> bf16 transposed [out][in] ----------
__global__ void wcvt_kernel(const float* __restrict__ wq, const float* __restrict__ wk,
                            const float* __restrict__ wv, const float* __restrict__ wp,
                            const float* __restrict__ w1, const float* __restrict__ w2,
                            unsigned short* __restrict__ wqT, unsigned short* __restrict__ wkT,
                            unsigned short* __restrict__ wvT, unsigned short* __restrict__ wpT,
                            unsigned short* __restrict__ w1T, unsigned short* __restrict__ w2T) {
    int idx = blockIdx.x * 256 + threadIdx.x;  // 131072 total
    if (idx < 49152) {
        int m = idx >> 14;
        int local = idx & 16383;
        int n = local >> 7, kk = local & 127;
        const float* w = (m == 0) ? wq : ((m == 1) ? wk : wv);
        unsigned short* o = (m == 0) ? wqT : ((m == 1) ? wkT : wvT);
        o[local] = f2bf(w[kk * 128 + n]);
    } else if (idx < 65536) {
        // wpT with k-dim pair-permuted within each 32-block (matches A1 layout)
        int local = idx - 49152;
        int n = local >> 7, kk = local & 127;
        int b = kk >> 5, j = kk & 31;
        int ko = b * 32 + ((j & 1) ? 16 + (j >> 1) : (j >> 1));
        wpT[local] = f2bf(wp[ko * 128 + n]);
    } else if (idx < 98304) {
        int local = idx - 65536;
        int n = local >> 7, kk = local & 127;
        w1T[local] = f2bf(w1[kk * 256 + n]);
    } else {
        int local = idx - 98304;
        int n = local >> 8, kk = local & 255;
        w2T[local] = f2bf(w2[kk * 128 + n]);
    }
}

// ---------- LayerNorm: 16 positions x 128 d per block, coalesced ----------
__global__ __launch_bounds__(256) void ln_kernel(
    const float* __restrict__ qi, const float* __restrict__ ki, const float* __restrict__ vi,
    const float* __restrict__ qw, const float* __restrict__ qb,
    const float* __restrict__ kw, const float* __restrict__ kb,
    const float* __restrict__ vw, const float* __restrict__ vb,
    unsigned short* __restrict__ xq, unsigned short* __restrict__ xk,
    unsigned short* __restrict__ xv) {
    __shared__ float lds[16 * 132];
    int bid = blockIdx.x, t = threadIdx.x;
    const float* src; unsigned short* dst; const float *g, *b;
    int S, valid;
    if (bid < 157) {
        int p0 = bid * 16;
        src = qi + p0; S = Q; dst = xq + p0 * D; g = qw; b = qb;
        valid = Q - p0; if (valid > 16) valid = 16;
    } else if (bid < 787) {
        int tt = bid - 157;
        int n = tt / 105, r = (tt - n * 105) * 16;
        src = ki + (size_t)(n * 128) * 1680 + r; S = 1680;
        dst = xk + (n * 1680 + r) * D; g = kw; b = kb; valid = 16;
    } else {
        int tt = bid - 787;
        int n = tt / 105, r = (tt - n * 105) * 16;
        src = vi + (size_t)(n * 128) * 1680 + r; S = 1680;
        dst = xv + (n * 1680 + r) * D; g = vw; b = vb; valid = 16;
    }
    int c4 = t & 3, d = t >> 2;
    floatx4 fa = {0.f, 0.f, 0.f, 0.f}, fb = {0.f, 0.f, 0.f, 0.f};
    if (c4 * 4 < valid) {
        fa = *(const floatx4*)(src + d * S + c4 * 4);
        fb = *(const floatx4*)(src + (d + 64) * S + c4 * 4);
    }
    #pragma unroll
    for (int j = 0; j < 4; j++) {
        lds[(c4 * 4 + j) * 132 + d] = fa[j];
        lds[(c4 * 4 + j) * 132 + d + 64] = fb[j];
    }
    __syncthreads();
    int lane = t & 63, wv = t >> 6;
    int pos = wv * 4 + (lane >> 4), l15 = lane & 15;
    floatx4 xa = *(const floatx4*)(&lds[pos * 132 + l15 * 8]);
    floatx4 xb = *(const floatx4*)(&lds[pos * 132 + l15 * 8 + 4]);
    float s = 0.f, ss = 0.f;
    #pragma unroll
    for (int j = 0; j < 4; j++) { s += xa[j] + xb[j]; ss += xa[j] * xa[j] + xb[j] * xb[j]; }
    #pragma unroll
    for (int m = 1; m <= 8; m <<= 1) { s += __shfl_xor(s, m, 64); ss += __shfl_xor(ss, m, 64); }
    float mean = s * (1.0f / 128.0f);
    float var = ss * (1.0f / 128.0f) - mean * mean;
    float rstd = rsqrtf(var + 1e-5f);
    floatx4 g0 = *(const floatx4*)(g + l15 * 8), g1 = *(const floatx4*)(g + l15 * 8 + 4);
    floatx4 b0 = *(const floatx4*)(b + l15 * 8), b1 = *(const floatx4*)(b + l15 * 8 + 4);
    short8 o;
    #pragma unroll
    for (int j = 0; j < 4; j++) {
        o[j] = (short)f2bf((xa[j] - mean) * rstd * g0[j] + b0[j]);
        o[4 + j] = (short)f2bf((xb[j] - mean) * rstd * g1[j] + b1[j]);
    }
    if (pos < valid) *(short8*)(dst + pos * D + l15 * 8) = o;
}

// ---------- Projection GEMM, vectorized weights; V written transposed+permuted ----------
__global__ __launch_bounds__(256) void proj_kernel(
    const unsigned short* __restrict__ xq, const unsigned short* __restrict__ xk,
    const unsigned short* __restrict__ xv,
    const unsigned short* __restrict__ wqT, const unsigned short* __restrict__ wkT,
    const unsigned short* __restrict__ wvT,
    const float* __restrict__ bq, const float* __restrict__ bk, const float* __restrict__ bv,
    unsigned short* __restrict__ qh, unsigned short* __restrict__ kh,
    unsigned short* __restrict__ vhT) {
    __shared__ short vlds[128 * 72];
    int bid = blockIdx.x;
    const unsigned short *src, *wT; const float* bias; int mb, mode; float scale;
    if (bid < 40)       { mode = 0; src = xq; wT = wqT; bias = bq; mb = bid * 64; scale = QSCALE; }
    else if (bid < 198) { mode = 1; src = xk; wT = wkT; bias = bk; mb = (bid - 40) * 64; scale = 1.0f; }
    else                { mode = 2; src = xv; wT = wvT; bias = bv; mb = (bid - 198) * 64; scale = 1.0f; }
    int t = threadIdx.x, wave = t >> 6, lane = t & 63;
    int l15 = lane & 15, quad = lane >> 4;
    int m0 = mb + wave * 16;
    floatx4 acc[8];
    #pragma unroll
    for (int i = 0; i < 8; i++) acc[i] = (floatx4){0.f, 0.f, 0.f, 0.f};
    #pragma unroll
    for (int kf = 0; kf < 4; kf++) {
        short8 A = *(const short8*)(src + (m0 + l15) * D + kf * 32 + quad * 8);
        #pragma unroll
        for (int nt = 0; nt < 8; nt++) {
            short8 Bv = *(const short8*)(wT + (nt * 16 + l15) * D + kf * 32 + quad * 8);
            acc[nt] = __builtin_amdgcn_mfma_f32_16x16x32_bf16(A, Bv, acc[nt], 0, 0, 0);
        }
    }
    if (mode != 2) {
        unsigned short* dst = (mode == 0) ? qh : kh;
        #pragma unroll
        for (int nt = 0; nt < 8; nt++) {
            float bb = bias[nt * 16 + l15];
            #pragma unroll
            for (int r = 0; r < 4; r++)
                dst[(m0 + quad * 4 + r) * D + nt * 16 + l15] = f2bf((acc[nt][r] + bb) * scale);
        }
    } else {
        #pragma unroll
        for (int nt = 0; nt < 8; nt++) {
            float bb = bias[nt * 16 + l15];
            #pragma unroll
            for (int r = 0; r < 4; r++)
                vlds[(nt * 16 + l15) * 72 + (wave * 16 + quad * 4 + r)] =
                    (short)f2bf(acc[nt][r] + bb);
        }
        __syncthreads();
        int pr = t & 31, dd = t >> 5;
        int sub = pr >> 4, i = pr & 15;
        #pragma unroll
        for (int pass = 0; pass < 16; pass++) {
            int d = pass * 8 + dd;
            unsigned lo = (unsigned short)vlds[d * 72 + sub * 32 + i];
            unsigned hi = (unsigned short)vlds[d * 72 + sub * 32 + 16 + i];
            *(unsigned*)(vhT + (size_t)d * NKPAD + mb + sub * 32 + 2 * i) = lo | (hi << 16);
        }
    }
}

// ---------- Fused attention: wave = 16 q-rows x 4 heads; 35 NK-splits ----------
__global__ __launch_bounds__(256) void attn_kernel(
    const unsigned short* __restrict__ qh, const unsigned short* __restrict__ kh,
    const unsigned short* __restrict__ vhT,
    const float* __restrict__ Wl, const int* __restrict__ vis,
    unsigned* __restrict__ OpartU, float* __restrict__ lpart) {
    __shared__ unsigned pP[4 * 4 * 16 * 20];  // [wave][head][row][20 u32 slots]
    int bid = blockIdx.x;
    int split = bid % SPLITS, qt = bid / SPLITS;
    int t = threadIdx.x, wave = t >> 6, lane = t & 63;
    int l15 = lane & 15, quad = lane >> 4;
    int qb = qt * 64 + wave * 16;
    int k00 = split * (CPS * 32);
    unsigned* pw = pP + wave * 1280;

    short8 qA[4];
    #pragma unroll
    for (int h = 0; h < 4; h++)
        qA[h] = *(const short8*)(qh + (qb + l15) * D + h * 32 + quad * 8);

    const float* wrow[4]; const int* vrow[4];
    #pragma unroll
    for (int r = 0; r < 4; r++) {
        int row = qb + quad * 4 + r;
        row = row < Q ? row : (Q - 1);
        wrow[r] = Wl + (size_t)row * NK;
        vrow[r] = vis + (size_t)row * NK;
    }

    const floatx4 zf = {0.f, 0.f, 0.f, 0.f};
    floatx4 O[4][2];
    float lacc[4][4];
    #pragma unroll
    for (int h = 0; h < 4; h++) {
        O[h][0] = zf; O[h][1] = zf;
        #pragma unroll
        for (int r = 0; r < 4; r++) lacc[h][r] = 0.f;
    }

    #pragma unroll 1
    for (int c = 0; c < CPS; c++) {
        int k0 = k00 + c * 32;
        float w0[4], w1[4]; int msk0[4], msk1[4];
        #pragma unroll
        for (int r = 0; r < 4; r++) {
            w0[r] = wrow[r][k0 + l15];
            w1[r] = wrow[r][k0 + 16 + l15];
            msk0[r] = vrow[r][k0 + l15];
            msk1[r] = vrow[r][k0 + 16 + l15];
        }
        #pragma unroll
        for (int h = 0; h < 4; h++) {
            short8 kB0 = *(const short8*)(kh + (k0 + l15) * D + h * 32 + quad * 8);
            short8 kB1 = *(const short8*)(kh + (k0 + 16 + l15) * D + h * 32 + quad * 8);
            floatx4 S0 = __builtin_amdgcn_mfma_f32_16x16x32_bf16(qA[h], kB0, zf, 0, 0, 0);
            floatx4 S1 = __builtin_amdgcn_mfma_f32_16x16x32_bf16(qA[h], kB1, zf, 0, 0, 0);
            #pragma unroll
            for (int r = 0; r < 4; r++) {
                float L0 = (msk0[r] ? S0[r] : NEGBIG) * w0[r];
                float L1 = (msk1[r] ? S1[r] : NEGBIG) * w1[r];
                float p0 = exp2f(L0), p1 = exp2f(L1);
                lacc[h][r] += p0 + p1;
                pw[h * 320 + (quad * 4 + r) * 20 + l15] = pack2bf(p0, p1);
            }
        }
        #pragma unroll
        for (int h = 0; h < 4; h++) {
            short8 P = *(const short8*)(pw + h * 320 + l15 * 20 + quad * 4);
            short8 vB0 = *(const short8*)(vhT + (size_t)(h * 32 + l15) * NKPAD + k0 + quad * 8);
            short8 vB1 = *(const short8*)(vhT + (size_t)(h * 32 + 16 + l15) * NKPAD + k0 + quad * 8);
            O[h][0] = __builtin_amdgcn_mfma_f32_16x16x32_bf16(P, vB0, O[h][0], 0, 0, 0);
            O[h][1] = __builtin_amdgcn_mfma_f32_16x16x32_bf16(P, vB1, O[h][1], 0, 0, 0);
        }
    }

    #pragma unroll
    for (int h = 0; h < 4; h++)
        #pragma unroll
        for (int r = 0; r < 4; r++) {
            float lv = lacc[h][r];
            lv += __shfl_xor(lv, 1, 64);
            lv += __shfl_xor(lv, 2, 64);
            lv += __shfl_xor(lv, 4, 64);
            lv += __shfl_xor(lv, 8, 64);
            int row = qb + quad * 4 + r;
            int base = (split * QPAD + row) * 4 + h;
            if (l15 == 0) lpart[base] = lv;
            OpartU[base * 16 + l15] = pack2bf(O[h][0][r], O[h][1][r]);
        }
}

// ---------- l-sum inverse ----------
__global__ void linv_kernel(const float* __restrict__ lpart, float* __restrict__ linv) {
    int i = blockIdx.x * 256 + threadIdx.x;  // 10240
    float s = 0.f;
    #pragma unroll 1
    for (int sp = 0; sp < SPLITS; sp++) s += lpart[sp * QPAD * 4 + i];
    linv[i] = 1.0f / fmaxf(s, 1e-30f);
}

// ---------- combine splits -> A1 (bf16, pair-permuted d layout) ----------
__global__ void combine_kernel(const unsigned* __restrict__ OpartU,
                               const float* __restrict__ linv,
                               unsigned* __restrict__ A1u) {
    int idx = blockIdx.x * 256 + threadIdx.x;  // 163840 = 2560*64
    float lo = 0.f, hi = 0.f;
    #pragma unroll 1
    for (int sp = 0; sp < SPLITS; sp++) {
        unsigned u = OpartU[(size_t)sp * (QPAD * 64) + idx];
        lo += bflo(u);
        hi += bfhi(u);
    }
    int q = idx >> 6, t6 = idx & 63;
    float inv = linv[q * 4 + (t6 >> 4)];
    A1u[idx] = pack2bf(lo * inv, hi * inv);
}

// ---------- MLP epilogue: wp + skip + preLN + MLP(gelu) + postLN + transpose ----------
__global__ __launch_bounds__(256) void mlp_kernel(
    const unsigned short* __restrict__ A1s, const unsigned short* __restrict__ wpT,
    const float* __restrict__ bp, const float* __restrict__ skip,
    const float* __restrict__ pre_w, const float* __restrict__ pre_b,
    const unsigned short* __restrict__ w1T, const float* __restrict__ b1,
    const unsigned short* __restrict__ w2T, const float* __restrict__ b2,
    const float* __restrict__ post_w, const float* __restrict__ post_b,
    float* __restrict__ out) {
    __shared__ __align__(16) char smem[51200];
    short* Z1 = (short*)smem;              // [64][136]
    short* H1 = (short*)(smem + 17408);    // [64][264]
    float* Zout = (float*)smem;            // [128][65] overlay after barrier

    int qb = blockIdx.x * 64;
    int t = threadIdx.x, wave = t >> 6, lane = t & 63;
    int l15 = lane & 15, quad = lane >> 4;
    int m0 = wave * 16;

    // G1: Z = A1 @ wp (both k-permuted identically)
    floatx4 z[8];
    #pragma unroll
    for (int i = 0; i < 8; i++) z[i] = (floatx4){0.f, 0.f, 0.f, 0.f};
    #pragma unroll
    for (int kf = 0; kf < 4; kf++) {
        short8 A = *(const short8*)(A1s + (qb + m0 + l15) * D + kf * 32 + quad * 8);
        #pragma unroll
        for (int nt = 0; nt < 8; nt++) {
            short8 Bv = *(const short8*)(wpT + (nt * 16 + l15) * D + kf * 32 + quad * 8);
            z[nt] = __builtin_amdgcn_mfma_f32_16x16x32_bf16(A, Bv, z[nt], 0, 0, 0);
        }
    }
    float Zv[8][4];
    #pragma unroll
    for (int nt = 0; nt < 8; nt++) {
        int n = nt * 16 + l15;
        float bb = bp[n];
        #pragma unroll
        for (int r = 0; r < 4; r++) {
            int q = qb + m0 + quad * 4 + r;
            int qc = q < Q ? q : (Q - 1);
            Zv[nt][r] = z[nt][r] + bb + skip[n * Q + qc];
        }
    }
    // pre-LN
    float Zn[8][4];
    {
        #pragma unroll
        for (int r = 0; r < 4; r++) {
            float s1 = 0.f, s2 = 0.f;
            #pragma unroll
            for (int nt = 0; nt < 8; nt++) { s1 += Zv[nt][r]; s2 += Zv[nt][r] * Zv[nt][r]; }
            #pragma unroll
            for (int m = 1; m <= 8; m <<= 1) { s1 += __shfl_xor(s1, m, 64); s2 += __shfl_xor(s2, m, 64); }
            float mean = s1 * (1.0f / 128.0f);
            float var = s2 * (1.0f / 128.0f) - mean * mean;
            float rstd = rsqrtf(var + 1e-5f);
            #pragma unroll
            for (int nt = 0; nt < 8; nt++) Zn[nt][r] = (Zv[nt][r] - mean) * rstd;
        }
        #pragma unroll
        for (int nt = 0; nt < 8; nt++) {
            int n = nt * 16 + l15;
            float g = pre_w[n], be = pre_b[n];
            #pragma unroll
            for (int r = 0; r < 4; r++) {
                Zn[nt][r] = Zn[nt][r] * g + be;
                Z1[(m0 + quad * 4 + r) * 136 + n] = (short)f2bf(Zn[nt][r]);
            }
        }
    }
    // G2: H = gelu(Z1 @ w1 + b1)
    {
        floatx4 h2[16];
        #pragma unroll
        for (int i = 0; i < 16; i++) h2[i] = (floatx4){0.f, 0.f, 0.f, 0.f};
        #pragma unroll
        for (int kf = 0; kf < 4; kf++) {
            short8 A = *(const short8*)(Z1 + (m0 + l15) * 136 + kf * 32 + quad * 8);
            #pragma unroll
            for (int nt = 0; nt < 16; nt++) {
                short8 Bv = *(const short8*)(w1T + (nt * 16 + l15) * D + kf * 32 + quad * 8);
                h2[nt] = __builtin_amdgcn_mfma_f32_16x16x32_bf16(A, Bv, h2[nt], 0, 0, 0);
            }
        }
        #pragma unroll
        for (int nt = 0; nt < 16; nt++) {
            int n = nt * 16 + l15;
            float bb = b1[n];
            #pragma unroll
            for (int r = 0; r < 4; r++) {
                float x = h2[nt][r] + bb;
                float gl = 0.5f * x * (1.0f + erff(x * 0.70710678118654752f));
                H1[(m0 + quad * 4 + r) * 264 + n] = (short)f2bf(gl);
            }
        }
    }
    // G3: R = H1 @ w2 + b2; Z2 = Zn + R
    floatx4 o3[8];
    #pragma unroll
    for (int i = 0; i < 8; i++) o3[i] = (floatx4){0.f, 0.f, 0.f, 0.f};
    #pragma unroll
    for (int kf = 0; kf < 8; kf++) {
        short8 A = *(const short8*)(H1 + (m0 + l15) * 264 + kf * 32 + quad * 8);
        #pragma unroll
        for (int nt = 0; nt < 8; nt++) {
            short8 Bv = *(const short8*)(w2T + (nt * 16 + l15) * 256 + kf * 32 + quad * 8);
            o3[nt] = __builtin_amdgcn_mfma_f32_16x16x32_bf16(A, Bv, o3[nt], 0, 0, 0);
        }
    }
    float Z2[8][4];
    #pragma unroll
    for (int nt = 0; nt < 8; nt++) {
        int n = nt * 16 + l15;
        float bb = b2[n];
        #pragma unroll
        for (int r = 0; r < 4; r++) Z2[nt][r] = Zn[nt][r] + o3[nt][r] + bb;
    }
    // post-LN
    float Zo[8][4];
    {
        #pragma unroll
        for (int r = 0; r < 4; r++) {
            float s1 = 0.f, s2 = 0.f;
            #pragma unroll
            for (int nt = 0; nt < 8; nt++) { s1 += Z2[nt][r]; s2 += Z2[nt][r] * Z2[nt][r]; }
            #pragma unroll
            for (int m = 1; m <= 8; m <<= 1) { s1 += __shfl_xor(s1, m, 64); s2 += __shfl_xor(s2, m, 64); }
            float mean = s1 * (1.0f / 128.0f);
            float var = s2 * (1.0f / 128.0f) - mean * mean;
            float rstd = rsqrtf(var + 1e-5f);
            #pragma unroll
            for (int nt = 0; nt < 8; nt++) Zo[nt][r] = (Z2[nt][r] - mean) * rstd;
        }
        #pragma unroll
        for (int nt = 0; nt < 8; nt++) {
            int n = nt * 16 + l15;
            float g = post_w[n], be = post_b[n];
            #pragma unroll
            for (int r = 0; r < 4; r++) Zo[nt][r] = Zo[nt][r] * g + be;
        }
    }
    __syncthreads();
    #pragma unroll
    for (int nt = 0; nt < 8; nt++)
        #pragma unroll
        for (int r = 0; r < 4; r++)
            Zout[(nt * 16 + l15) * 65 + m0 + quad * 4 + r] = Zo[nt][r];
    __syncthreads();
    {
        int pl = t & 63;
        int q = qb + pl;
        if (q < Q) {
            #pragma unroll
            for (int it = 0; it < 32; it++) {
                int n = it * 4 + (t >> 6);
                out[n * Q + q] = Zout[n * 65 + pl];
            }
        }
    }
}

extern "C" void kernel_launch(void* const* d_in, const int* in_sizes, int n_in,
                              void* d_out, int out_size, void* d_ws, size_t ws_size,
                              hipStream_t stream) {
    (void)in_sizes; (void)n_in; (void)out_size; (void)ws_size;
    const float* q      = (const float*)d_in[0];
    const float* k      = (const float*)d_in[1];
    const float* v      = (const float*)d_in[2];
    const float* Wl     = (const float*)d_in[3];
    const int*   vis    = (const int*)  d_in[4];
    const float* skip   = (const float*)d_in[5];
    const float* qn_w   = (const float*)d_in[6];
    const float* qn_b   = (const float*)d_in[7];
    const float* kn_w   = (const float*)d_in[8];
    const float* kn_b   = (const float*)d_in[9];
    const float* vn_w   = (const float*)d_in[10];
    const float* vn_b   = (const float*)d_in[11];
    const float* pre_w  = (const float*)d_in[12];
    const float* pre_b  = (const float*)d_in[13];
    const float* post_w = (const float*)d_in[14];
    const float* post_b = (const float*)d_in[15];
    const float* wq     = (const float*)d_in[16];
    const float* bq     = (const float*)d_in[17];
    const float* wk     = (const float*)d_in[18];
    const float* bk     = (const float*)d_in[19];
    const float* wv     = (const float*)d_in[20];
    const float* bv     = (const float*)d_in[21];
    const float* wp     = (const float*)d_in[22];
    const float* bp     = (const float*)d_in[23];
    const float* w1     = (const float*)d_in[24];
    const float* b1     = (const float*)d_in[25];
    const float* w2     = (const float*)d_in[26];
    const float* b2     = (const float*)d_in[27];
    float* out = (float*)d_out;

    char* ws = (char*)d_ws;
    unsigned short* xq  = (unsigned short*)(ws + 0);          //  2560*128 bf16
    unsigned short* xk  = (unsigned short*)(ws + 655360);     // 10112*128 bf16
    unsigned short* xv  = (unsigned short*)(ws + 3244032);
    unsigned short* qh  = (unsigned short*)(ws + 5832704);
    unsigned short* kh  = (unsigned short*)(ws + 6488064);
    unsigned short* vhT = (unsigned short*)(ws + 9076736);    // [128][10112] bf16, pair-permuted
    unsigned short* wqT = (unsigned short*)(ws + 11665408);
    unsigned short* wkT = (unsigned short*)(ws + 11698176);
    unsigned short* wvT = (unsigned short*)(ws + 11730944);
    unsigned short* wpT = (unsigned short*)(ws + 11763712);
    unsigned short* w1T = (unsigned short*)(ws + 11796480);
    unsigned short* w2T = (unsigned short*)(ws + 11862016);
    unsigned* OpartU    = (unsigned*)(ws + 11927552);         // 35*2560*4*16 u32
    float* lpart        = (float*)(ws + 34865152);            // 35*2560*4 f32
    float* linv         = (float*)(ws + 36298752);            // 2560*4 f32
    unsigned* A1u       = (unsigned*)(ws + 36339712);         // 2560*64 u32
    // total ws used: 36995072 bytes

    wcvt_kernel<<<dim3(512), dim3(256), 0, stream>>>(wq, wk, wv, wp, w1, w2,
                                                     wqT, wkT, wvT, wpT, w1T, w2T);
    ln_kernel<<<dim3(1417), dim3(256), 0, stream>>>(q, k, v, qn_w, qn_b, kn_w, kn_b, vn_w, vn_b,
                                                    xq, xk, xv);
    proj_kernel<<<dim3(356), dim3(256), 0, stream>>>(xq, xk, xv, wqT, wkT, wvT, bq, bk, bv,
                                                     qh, kh, vhT);
    attn_kernel<<<dim3(40 * SPLITS), dim3(256), 0, stream>>>(qh, kh, vhT, Wl, vis, OpartU, lpart);
    linv_kernel<<<dim3(40), dim3(256), 0, stream>>>(lpart, linv);
    combine_kernel<<<dim3(640), dim3(256), 0, stream>>>(OpartU, linv, A1u);
    mlp_kernel<<<dim3(40), dim3(256), 0, stream>>>((const unsigned short*)A1u, wpT, bp, skip,
                                                   pre_w, pre_b, w1T, b1, w2T, b2,
                                                   post_w, post_b, out);
}

// Round 3
// 412.010 us; speedup vs baseline: 1.0528x; 1.0341x over previous
//
#include <hip/hip_runtime.h>
#include <hip/hip_bf16.h>
#include <math.h>

typedef short short8 __attribute__((ext_vector_type(8)));
typedef float floatx4 __attribute__((ext_vector_type(4)));

#define D 128
#define Q 2500
#define QPAD 2560
#define NK 10080
#define NKPAD 10112
#define SPLITS 35
#define CPS 9  // chunks of 32 k per split; 35*9*32 = 10080
// padded strides (avoid 4096B channel alignment)
#define OPS 163920   // u32 per split for OpartU (163840 + 80)
#define LPS 10308    // f32 per split for lpart (10240 + 68)
// 1/sqrt(32) * log2(e)
#define QSCALE 0.25501268426834347f
#define NEGBIG -3.0e38f

__device__ __forceinline__ unsigned short f2bf(float f) {
    unsigned u = __float_as_uint(f);
    unsigned r = (u + 0x7fffu + ((u >> 16) & 1u)) >> 16;
    return (unsigned short)r;
}
__device__ __forceinline__ unsigned pack2bf(float lo, float hi) {
    unsigned u0 = __float_as_uint(lo) + 0x8000u;
    unsigned u1 = __float_as_uint(hi) + 0x8000u;
    return (u0 >> 16) | (u1 & 0xffff0000u);
}
__device__ __forceinline__ float bflo(unsigned u) { return __uint_as_float(u << 16); }
__device__ __forceinline__ float bfhi(unsigned u) { return __uint_as_float(u & 0xffff0000u); }
// bf16(W) with vis packed into sign bit (W >= 0 always)
__device__ __forceinline__ unsigned packwv(float w, int v) {
    unsigned b = __float_as_uint(w);
    unsigned r = (b + 0x7fffu + ((b >> 16) & 1u)) >> 16;
    return v ? r : (r | 0x8000u);
}

// ---------- weight convert: fp32 [in][out] -> bf16 transposed [out][in] ----------
__global__ void wcvt_kernel(const float* __restrict__ wq, const float* __restrict__ wk,
                            const float* __restrict__ wv, const float* __restrict__ wp,
                            const float* __restrict__ w1, const float* __restrict__ w2,
                            unsigned short* __restrict__ wqT, unsigned short* __restrict__ wkT,
                            unsigned short* __restrict__ wvT, unsigned short* __restrict__ wpT,
                            unsigned short* __restrict__ w1T, unsigned short* __restrict__ w2T) {
    int idx = blockIdx.x * 256 + threadIdx.x;  // 131072 total
    if (idx < 49152) {
        int m = idx >> 14;
        int local = idx & 16383;
        int n = local >> 7, kk = local & 127;
        const float* w = (m == 0) ? wq : ((m == 1) ? wk : wv);
        unsigned short* o = (m == 0) ? wqT : ((m == 1) ? wkT : wvT);
        o[local] = f2bf(w[kk * 128 + n]);
    } else if (idx < 65536) {
        // wpT with k-dim pair-permuted within each 32-block (matches A1 layout)
        int local = idx - 49152;
        int n = local >> 7, kk = local & 127;
        int b = kk >> 5, j = kk & 31;
        int ko = b * 32 + ((j & 1) ? 16 + (j >> 1) : (j >> 1));
        wpT[local] = f2bf(wp[ko * 128 + n]);
    } else if (idx < 98304) {
        int local = idx - 65536;
        int n = local >> 7, kk = local & 127;
        w1T[local] = f2bf(w1[kk * 256 + n]);
    } else {
        int local = idx - 98304;
        int n = local >> 8, kk = local & 255;
        w2T[local] = f2bf(w2[kk * 128 + n]);
    }
}

// ---------- LayerNorm: 16 positions x 128 d per block, coalesced ----------
__global__ __launch_bounds__(256) void ln_kernel(
    const float* __restrict__ qi, const float* __restrict__ ki, const float* __restrict__ vi,
    const float* __restrict__ qw, const float* __restrict__ qb,
    const float* __restrict__ kw, const float* __restrict__ kb,
    const float* __restrict__ vw, const float* __restrict__ vb,
    unsigned short* __restrict__ xq, unsigned short* __restrict__ xk,
    unsigned short* __restrict__ xv) {
    __shared__ float lds[16 * 132];
    int bid = blockIdx.x, t = threadIdx.x;
    const float* src; unsigned short* dst; const float *g, *b;
    int S, valid;
    if (bid < 157) {
        int p0 = bid * 16;
        src = qi + p0; S = Q; dst = xq + p0 * D; g = qw; b = qb;
        valid = Q - p0; if (valid > 16) valid = 16;
    } else if (bid < 787) {
        int tt = bid - 157;
        int n = tt / 105, r = (tt - n * 105) * 16;
        src = ki + (size_t)(n * 128) * 1680 + r; S = 1680;
        dst = xk + (n * 1680 + r) * D; g = kw; b = kb; valid = 16;
    } else {
        int tt = bid - 787;
        int n = tt / 105, r = (tt - n * 105) * 16;
        src = vi + (size_t)(n * 128) * 1680 + r; S = 1680;
        dst = xv + (n * 1680 + r) * D; g = vw; b = vb; valid = 16;
    }
    int c4 = t & 3, d = t >> 2;
    floatx4 fa = {0.f, 0.f, 0.f, 0.f}, fb = {0.f, 0.f, 0.f, 0.f};
    if (c4 * 4 < valid) {
        fa = *(const floatx4*)(src + d * S + c4 * 4);
        fb = *(const floatx4*)(src + (d + 64) * S + c4 * 4);
    }
    #pragma unroll
    for (int j = 0; j < 4; j++) {
        lds[(c4 * 4 + j) * 132 + d] = fa[j];
        lds[(c4 * 4 + j) * 132 + d + 64] = fb[j];
    }
    __syncthreads();
    int lane = t & 63, wv = t >> 6;
    int pos = wv * 4 + (lane >> 4), l15 = lane & 15;
    floatx4 xa = *(const floatx4*)(&lds[pos * 132 + l15 * 8]);
    floatx4 xb = *(const floatx4*)(&lds[pos * 132 + l15 * 8 + 4]);
    float s = 0.f, ss = 0.f;
    #pragma unroll
    for (int j = 0; j < 4; j++) { s += xa[j] + xb[j]; ss += xa[j] * xa[j] + xb[j] * xb[j]; }
    #pragma unroll
    for (int m = 1; m <= 8; m <<= 1) { s += __shfl_xor(s, m, 64); ss += __shfl_xor(ss, m, 64); }
    float mean = s * (1.0f / 128.0f);
    float var = ss * (1.0f / 128.0f) - mean * mean;
    float rstd = rsqrtf(var + 1e-5f);
    floatx4 g0 = *(const floatx4*)(g + l15 * 8), g1 = *(const floatx4*)(g + l15 * 8 + 4);
    floatx4 b0 = *(const floatx4*)(b + l15 * 8), b1 = *(const floatx4*)(b + l15 * 8 + 4);
    short8 o;
    #pragma unroll
    for (int j = 0; j < 4; j++) {
        o[j] = (short)f2bf((xa[j] - mean) * rstd * g0[j] + b0[j]);
        o[4 + j] = (short)f2bf((xb[j] - mean) * rstd * g1[j] + b1[j]);
    }
    if (pos < valid) *(short8*)(dst + pos * D + l15 * 8) = o;
}

// ---------- Projection GEMM, vectorized weights; V written transposed+permuted ----------
__global__ __launch_bounds__(256) void proj_kernel(
    const unsigned short* __restrict__ xq, const unsigned short* __restrict__ xk,
    const unsigned short* __restrict__ xv,
    const unsigned short* __restrict__ wqT, const unsigned short* __restrict__ wkT,
    const unsigned short* __restrict__ wvT,
    const float* __restrict__ bq, const float* __restrict__ bk, const float* __restrict__ bv,
    unsigned short* __restrict__ qh, unsigned short* __restrict__ kh,
    unsigned short* __restrict__ vhT) {
    __shared__ short vlds[128 * 72];
    int bid = blockIdx.x;
    const unsigned short *src, *wT; const float* bias; int mb, mode; float scale;
    if (bid < 40)       { mode = 0; src = xq; wT = wqT; bias = bq; mb = bid * 64; scale = QSCALE; }
    else if (bid < 198) { mode = 1; src = xk; wT = wkT; bias = bk; mb = (bid - 40) * 64; scale = 1.0f; }
    else                { mode = 2; src = xv; wT = wvT; bias = bv; mb = (bid - 198) * 64; scale = 1.0f; }
    int t = threadIdx.x, wave = t >> 6, lane = t & 63;
    int l15 = lane & 15, quad = lane >> 4;
    int m0 = mb + wave * 16;
    floatx4 acc[8];
    #pragma unroll
    for (int i = 0; i < 8; i++) acc[i] = (floatx4){0.f, 0.f, 0.f, 0.f};
    #pragma unroll
    for (int kf = 0; kf < 4; kf++) {
        short8 A = *(const short8*)(src + (m0 + l15) * D + kf * 32 + quad * 8);
        #pragma unroll
        for (int nt = 0; nt < 8; nt++) {
            short8 Bv = *(const short8*)(wT + (nt * 16 + l15) * D + kf * 32 + quad * 8);
            acc[nt] = __builtin_amdgcn_mfma_f32_16x16x32_bf16(A, Bv, acc[nt], 0, 0, 0);
        }
    }
    if (mode != 2) {
        unsigned short* dst = (mode == 0) ? qh : kh;
        #pragma unroll
        for (int nt = 0; nt < 8; nt++) {
            float bb = bias[nt * 16 + l15];
            #pragma unroll
            for (int r = 0; r < 4; r++)
                dst[(m0 + quad * 4 + r) * D + nt * 16 + l15] = f2bf((acc[nt][r] + bb) * scale);
        }
    } else {
        #pragma unroll
        for (int nt = 0; nt < 8; nt++) {
            float bb = bias[nt * 16 + l15];
            #pragma unroll
            for (int r = 0; r < 4; r++)
                vlds[(nt * 16 + l15) * 72 + (wave * 16 + quad * 4 + r)] =
                    (short)f2bf(acc[nt][r] + bb);
        }
        __syncthreads();
        int pr = t & 31, dd = t >> 5;
        int sub = pr >> 4, i = pr & 15;
        #pragma unroll
        for (int pass = 0; pass < 16; pass++) {
            int d = pass * 8 + dd;
            unsigned lo = (unsigned short)vlds[d * 72 + sub * 32 + i];
            unsigned hi = (unsigned short)vlds[d * 72 + sub * 32 + 16 + i];
            *(unsigned*)(vhT + (size_t)d * NKPAD + mb + sub * 32 + 2 * i) = lo | (hi << 16);
        }
    }
}

// ---------- Fused attention v3: coalesced W/vis + register prefetch ----------
__global__ __launch_bounds__(256) void attn_kernel(
    const unsigned short* __restrict__ qh, const unsigned short* __restrict__ kh,
    const unsigned short* __restrict__ vhT,
    const float* __restrict__ Wl, const int* __restrict__ vis,
    unsigned* __restrict__ OpartU, float* __restrict__ lpart) {
    __shared__ unsigned pP[4 * 4 * 16 * 20];    // P transform area, per-wave
    __shared__ unsigned wbuf[4 * 2 * 16 * 16];  // W/vis packed, per-wave double buffer
    int bid = blockIdx.x;
    int split = bid % SPLITS, qt = bid / SPLITS;
    int t = threadIdx.x, wave = t >> 6, lane = t & 63;
    int l15 = lane & 15, quad = lane >> 4;
    int qb = qt * 64 + wave * 16;
    int k00 = split * (CPS * 32);
    unsigned* pw = pP + wave * 1280;
    unsigned* wb = wbuf + wave * 512;
    unsigned short* wbs = (unsigned short*)wb;

    // Q fragments (loop-invariant)
    short8 qA[4];
    #pragma unroll
    for (int h = 0; h < 4; h++)
        qA[h] = *(const short8*)(qh + (size_t)(qb + l15) * D + h * 32 + quad * 8);

    // staging pointers: lane covers (row = lr [+8], k = lc*4..+3)
    int lr = lane >> 3, lc = lane & 7;
    int row0 = qb + lr;      row0 = row0 < Q ? row0 : Q - 1;
    int row1 = qb + 8 + lr;  row1 = row1 < Q ? row1 : Q - 1;
    const float* wp0 = Wl + (size_t)row0 * NK + k00 + lc * 4;
    const float* wp1 = Wl + (size_t)row1 * NK + k00 + lc * 4;
    const int*  vp0 = vis + (size_t)row0 * NK + k00 + lc * 4;
    const int*  vp1 = vis + (size_t)row1 * NK + k00 + lc * 4;

    const floatx4 zf = {0.f, 0.f, 0.f, 0.f};
    floatx4 O[4][2];
    float lacc[4][4];
    #pragma unroll
    for (int h = 0; h < 4; h++) {
        O[h][0] = zf; O[h][1] = zf;
        #pragma unroll
        for (int r = 0; r < 4; r++) lacc[h][r] = 0.f;
    }

    // prologue: load + stage chunk 0
    floatx4 wA0 = *(const floatx4*)(wp0);
    floatx4 wA1 = *(const floatx4*)(wp1);
    int4    vA0 = *(const int4*)(vp0);
    int4    vA1 = *(const int4*)(vp1);
    {
        uint2 s0, s1;
        s0.x = packwv(wA0[0], vA0.x) | (packwv(wA0[1], vA0.y) << 16);
        s0.y = packwv(wA0[2], vA0.z) | (packwv(wA0[3], vA0.w) << 16);
        s1.x = packwv(wA1[0], vA1.x) | (packwv(wA1[1], vA1.y) << 16);
        s1.y = packwv(wA1[2], vA1.z) | (packwv(wA1[3], vA1.w) << 16);
        *(uint2*)(wb + lr * 16 + lc * 2) = s0;
        *(uint2*)(wb + (8 + lr) * 16 + lc * 2) = s1;
    }

    for (int c = 0; c < CPS; c++) {
        int buf = c & 1;
        int k0 = k00 + c * 32;
        // prefetch next chunk's W/vis (HBM stream) while computing this chunk
        if (c + 1 < CPS) {
            wA0 = *(const floatx4*)(wp0 + (c + 1) * 32);
            wA1 = *(const floatx4*)(wp1 + (c + 1) * 32);
            vA0 = *(const int4*)(vp0 + (c + 1) * 32);
            vA1 = *(const int4*)(vp1 + (c + 1) * 32);
        }
        // decode packed W/vis -> per-element (a2,b2): L = S*a2 + b2
        float a2[8], b2[8];
        #pragma unroll
        for (int i = 0; i < 8; i++) {
            int rr = i >> 1, hf = i & 1;
            unsigned u = wbs[buf * 512 + (quad * 4 + rr) * 32 + hf * 16 + l15];
            float wf = __uint_as_float((u & 0x7fffu) << 16);
            bool msk = (u & 0x8000u) != 0;
            a2[i] = msk ? 0.f : wf;
            b2[i] = msk ? wf * NEGBIG : 0.f;
        }
        #pragma unroll
        for (int h = 0; h < 4; h++) {
            short8 kB0 = *(const short8*)(kh + (size_t)(k0 + l15) * D + h * 32 + quad * 8);
            short8 kB1 = *(const short8*)(kh + (size_t)(k0 + 16 + l15) * D + h * 32 + quad * 8);
            floatx4 S0 = __builtin_amdgcn_mfma_f32_16x16x32_bf16(qA[h], kB0, zf, 0, 0, 0);
            floatx4 S1 = __builtin_amdgcn_mfma_f32_16x16x32_bf16(qA[h], kB1, zf, 0, 0, 0);
            #pragma unroll
            for (int r = 0; r < 4; r++) {
                float p0 = exp2f(S0[r] * a2[2 * r] + b2[2 * r]);
                float p1 = exp2f(S1[r] * a2[2 * r + 1] + b2[2 * r + 1]);
                lacc[h][r] += p0 + p1;
                pw[h * 320 + (quad * 4 + r) * 20 + l15] = pack2bf(p0, p1);
            }
        }
        #pragma unroll
        for (int h = 0; h < 4; h++) {
            short8 P = *(const short8*)(pw + h * 320 + l15 * 20 + quad * 4);
            short8 vB0 = *(const short8*)(vhT + (size_t)(h * 32 + l15) * NKPAD + k0 + quad * 8);
            short8 vB1 = *(const short8*)(vhT + (size_t)(h * 32 + 16 + l15) * NKPAD + k0 + quad * 8);
            O[h][0] = __builtin_amdgcn_mfma_f32_16x16x32_bf16(P, vB0, O[h][0], 0, 0, 0);
            O[h][1] = __builtin_amdgcn_mfma_f32_16x16x32_bf16(P, vB1, O[h][1], 0, 0, 0);
        }
        // stage next chunk into the other buffer
        if (c + 1 < CPS) {
            uint2 s0, s1;
            s0.x = packwv(wA0[0], vA0.x) | (packwv(wA0[1], vA0.y) << 16);
            s0.y = packwv(wA0[2], vA0.z) | (packwv(wA0[3], vA0.w) << 16);
            s1.x = packwv(wA1[0], vA1.x) | (packwv(wA1[1], vA1.y) << 16);
            s1.y = packwv(wA1[2], vA1.z) | (packwv(wA1[3], vA1.w) << 16);
            int nbuf = (buf ^ 1) * 256;
            *(uint2*)(wb + nbuf + lr * 16 + lc * 2) = s0;
            *(uint2*)(wb + nbuf + (8 + lr) * 16 + lc * 2) = s1;
        }
    }

    #pragma unroll
    for (int h = 0; h < 4; h++)
        #pragma unroll
        for (int r = 0; r < 4; r++) {
            float lv = lacc[h][r];
            lv += __shfl_xor(lv, 1, 64);
            lv += __shfl_xor(lv, 2, 64);
            lv += __shfl_xor(lv, 4, 64);
            lv += __shfl_xor(lv, 8, 64);
            int row = qb + quad * 4 + r;
            if (l15 == 0) lpart[(size_t)split * LPS + row * 4 + h] = lv;
            OpartU[(size_t)split * OPS + (row * 4 + h) * 16 + l15] =
                pack2bf(O[h][0][r], O[h][1][r]);
        }
}

// ---------- l-sum inverse ----------
__global__ void linv_kernel(const float* __restrict__ lpart, float* __restrict__ linv) {
    int i = blockIdx.x * 256 + threadIdx.x;  // 10240
    float s = 0.f;
    #pragma unroll 7
    for (int sp = 0; sp < SPLITS; sp++) s += lpart[(size_t)sp * LPS + i];
    linv[i] = 1.0f / fmaxf(s, 1e-30f);
}

// ---------- combine splits -> A1 (bf16, pair-permuted d layout) ----------
__global__ void combine_kernel(const unsigned* __restrict__ OpartU,
                               const float* __restrict__ linv,
                               unsigned* __restrict__ A1u) {
    int idx = (blockIdx.x * 256 + threadIdx.x) * 4;  // grid 160 -> 163840 u32
    float lo0 = 0.f, lo1 = 0.f, lo2 = 0.f, lo3 = 0.f;
    float hi0 = 0.f, hi1 = 0.f, hi2 = 0.f, hi3 = 0.f;
    #pragma unroll 5
    for (int sp = 0; sp < SPLITS; sp++) {
        uint4 u = *(const uint4*)(OpartU + (size_t)sp * OPS + idx);
        lo0 += bflo(u.x); hi0 += bfhi(u.x);
        lo1 += bflo(u.y); hi1 += bfhi(u.y);
        lo2 += bflo(u.z); hi2 += bfhi(u.z);
        lo3 += bflo(u.w); hi3 += bfhi(u.w);
    }
    int q = idx >> 6;
    float inv = linv[q * 4 + ((idx & 63) >> 4)];
    uint4 o;
    o.x = pack2bf(lo0 * inv, hi0 * inv);
    o.y = pack2bf(lo1 * inv, hi1 * inv);
    o.z = pack2bf(lo2 * inv, hi2 * inv);
    o.w = pack2bf(lo3 * inv, hi3 * inv);
    *(uint4*)(A1u + idx) = o;
}

// ---------- MLP epilogue: wp + skip + preLN + MLP(gelu) + postLN + transpose ----------
__global__ __launch_bounds__(256) void mlp_kernel(
    const unsigned short* __restrict__ A1s, const unsigned short* __restrict__ wpT,
    const float* __restrict__ bp, const float* __restrict__ skip,
    const float* __restrict__ pre_w, const float* __restrict__ pre_b,
    const unsigned short* __restrict__ w1T, const float* __restrict__ b1,
    const unsigned short* __restrict__ w2T, const float* __restrict__ b2,
    const float* __restrict__ post_w, const float* __restrict__ post_b,
    float* __restrict__ out) {
    __shared__ __align__(16) char smem[51200];
    short* Z1 = (short*)smem;              // [64][136]
    short* H1 = (short*)(smem + 17408);    // [64][264]
    float* Zout = (float*)smem;            // [128][65] overlay after barrier

    int qb = blockIdx.x * 64;
    int t = threadIdx.x, wave = t >> 6, lane = t & 63;
    int l15 = lane & 15, quad = lane >> 4;
    int m0 = wave * 16;

    // G1: Z = A1 @ wp (both k-permuted identically)
    floatx4 z[8];
    #pragma unroll
    for (int i = 0; i < 8; i++) z[i] = (floatx4){0.f, 0.f, 0.f, 0.f};
    #pragma unroll
    for (int kf = 0; kf < 4; kf++) {
        short8 A = *(const short8*)(A1s + (qb + m0 + l15) * D + kf * 32 + quad * 8);
        #pragma unroll
        for (int nt = 0; nt < 8; nt++) {
            short8 Bv = *(const short8*)(wpT + (nt * 16 + l15) * D + kf * 32 + quad * 8);
            z[nt] = __builtin_amdgcn_mfma_f32_16x16x32_bf16(A, Bv, z[nt], 0, 0, 0);
        }
    }
    float Zv[8][4];
    #pragma unroll
    for (int nt = 0; nt < 8; nt++) {
        int n = nt * 16 + l15;
        float bb = bp[n];
        #pragma unroll
        for (int r = 0; r < 4; r++) {
            int q = qb + m0 + quad * 4 + r;
            int qc = q < Q ? q : (Q - 1);
            Zv[nt][r] = z[nt][r] + bb + skip[n * Q + qc];
        }
    }
    // pre-LN
    float Zn[8][4];
    {
        #pragma unroll
        for (int r = 0; r < 4; r++) {
            float s1 = 0.f, s2 = 0.f;
            #pragma unroll
            for (int nt = 0; nt < 8; nt++) { s1 += Zv[nt][r]; s2 += Zv[nt][r] * Zv[nt][r]; }
            #pragma unroll
            for (int m = 1; m <= 8; m <<= 1) { s1 += __shfl_xor(s1, m, 64); s2 += __shfl_xor(s2, m, 64); }
            float mean = s1 * (1.0f / 128.0f);
            float var = s2 * (1.0f / 128.0f) - mean * mean;
            float rstd = rsqrtf(var + 1e-5f);
            #pragma unroll
            for (int nt = 0; nt < 8; nt++) Zn[nt][r] = (Zv[nt][r] - mean) * rstd;
        }
        #pragma unroll
        for (int nt = 0; nt < 8; nt++) {
            int n = nt * 16 + l15;
            float g = pre_w[n], be = pre_b[n];
            #pragma unroll
            for (int r = 0; r < 4; r++) {
                Zn[nt][r] = Zn[nt][r] * g + be;
                Z1[(m0 + quad * 4 + r) * 136 + n] = (short)f2bf(Zn[nt][r]);
            }
        }
    }
    // G2: H = gelu(Z1 @ w1 + b1)
    {
        floatx4 h2[16];
        #pragma unroll
        for (int i = 0; i < 16; i++) h2[i] = (floatx4){0.f, 0.f, 0.f, 0.f};
        #pragma unroll
        for (int kf = 0; kf < 4; kf++) {
            short8 A = *(const short8*)(Z1 + (m0 + l15) * 136 + kf * 32 + quad * 8);
            #pragma unroll
            for (int nt = 0; nt < 16; nt++) {
                short8 Bv = *(const short8*)(w1T + (nt * 16 + l15) * D + kf * 32 + quad * 8);
                h2[nt] = __builtin_amdgcn_mfma_f32_16x16x32_bf16(A, Bv, h2[nt], 0, 0, 0);
            }
        }
        #pragma unroll
        for (int nt = 0; nt < 16; nt++) {
            int n = nt * 16 + l15;
            float bb = b1[n];
            #pragma unroll
            for (int r = 0; r < 4; r++) {
                float x = h2[nt][r] + bb;
                float gl = 0.5f * x * (1.0f + erff(x * 0.70710678118654752f));
                H1[(m0 + quad * 4 + r) * 264 + n] = (short)f2bf(gl);
            }
        }
    }
    // G3: R = H1 @ w2 + b2; Z2 = Zn + R
    floatx4 o3[8];
    #pragma unroll
    for (int i = 0; i < 8; i++) o3[i] = (floatx4){0.f, 0.f, 0.f, 0.f};
    #pragma unroll
    for (int kf = 0; kf < 8; kf++) {
        short8 A = *(const short8*)(H1 + (m0 + l15) * 264 + kf * 32 + quad * 8);
        #pragma unroll
        for (int nt = 0; nt < 8; nt++) {
            short8 Bv = *(const short8*)(w2T + (nt * 16 + l15) * 256 + kf * 32 + quad * 8);
            o3[nt] = __builtin_amdgcn_mfma_f32_16x16x32_bf16(A, Bv, o3[nt], 0, 0, 0);
        }
    }
    float Z2[8][4];
    #pragma unroll
    for (int nt = 0; nt < 8; nt++) {
        int n = nt * 16 + l15;
        float bb = b2[n];
        #pragma unroll
        for (int r = 0; r < 4; r++) Z2[nt][r] = Zn[nt][r] + o3[nt][r] + bb;
    }
    // post-LN
    float Zo[8][4];
    {
        #pragma unroll
        for (int r = 0; r < 4; r++) {
            float s1 = 0.f, s2 = 0.f;
            #pragma unroll
            for (int nt = 0; nt < 8; nt++) { s1 += Z2[nt][r]; s2 += Z2[nt][r] * Z2[nt][r]; }
            #pragma unroll
            for (int m = 1; m <= 8; m <<= 1) { s1 += __shfl_xor(s1, m, 64); s2 += __shfl_xor(s2, m, 64); }
            float mean = s1 * (1.0f / 128.0f);
            float var = s2 * (1.0f / 128.0f) - mean * mean;
            float rstd = rsqrtf(var + 1e-5f);
            #pragma unroll
            for (int nt = 0; nt < 8; nt++) Zo[nt][r] = (Z2[nt][r] - mean) * rstd;
        }
        #pragma unroll
        for (int nt = 0; nt < 8; nt++) {
            int n = nt * 16 + l15;
            float g = post_w[n], be = post_b[n];
            #pragma unroll
            for (int r = 0; r < 4; r++) Zo[nt][r] = Zo[nt][r] * g + be;
        }
    }
    __syncthreads();
    #pragma unroll
    for (int nt = 0; nt < 8; nt++)
        #pragma unroll
        for (int r = 0; r < 4; r++)
            Zout[(nt * 16 + l15) * 65 + m0 + quad * 4 + r] = Zo[nt][r];
    __syncthreads();
    {
        int pl = t & 63;
        int q = qb + pl;
        if (q < Q) {
            #pragma unroll
            for (int it = 0; it < 32; it++) {
                int n = it * 4 + (t >> 6);
                out[n * Q + q] = Zout[n * 65 + pl];
            }
        }
    }
}

extern "C" void kernel_launch(void* const* d_in, const int* in_sizes, int n_in,
                              void* d_out, int out_size, void* d_ws, size_t ws_size,
                              hipStream_t stream) {
    (void)in_sizes; (void)n_in; (void)out_size; (void)ws_size;
    const float* q      = (const float*)d_in[0];
    const float* k      = (const float*)d_in[1];
    const float* v      = (const float*)d_in[2];
    const float* Wl     = (const float*)d_in[3];
    const int*   vis    = (const int*)  d_in[4];
    const float* skip   = (const float*)d_in[5];
    const float* qn_w   = (const float*)d_in[6];
    const float* qn_b   = (const float*)d_in[7];
    const float* kn_w   = (const float*)d_in[8];
    const float* kn_b   = (const float*)d_in[9];
    const float* vn_w   = (const float*)d_in[10];
    const float* vn_b   = (const float*)d_in[11];
    const float* pre_w  = (const float*)d_in[12];
    const float* pre_b  = (const float*)d_in[13];
    const float* post_w = (const float*)d_in[14];
    const float* post_b = (const float*)d_in[15];
    const float* wq     = (const float*)d_in[16];
    const float* bq     = (const float*)d_in[17];
    const float* wk     = (const float*)d_in[18];
    const float* bk     = (const float*)d_in[19];
    const float* wv     = (const float*)d_in[20];
    const float* bv     = (const float*)d_in[21];
    const float* wp     = (const float*)d_in[22];
    const float* bp     = (const float*)d_in[23];
    const float* w1     = (const float*)d_in[24];
    const float* b1     = (const float*)d_in[25];
    const float* w2     = (const float*)d_in[26];
    const float* b2     = (const float*)d_in[27];
    float* out = (float*)d_out;

    char* ws = (char*)d_ws;
    unsigned short* xq  = (unsigned short*)(ws + 0);          //  2560*128 bf16
    unsigned short* xk  = (unsigned short*)(ws + 655360);     // 10112*128 bf16
    unsigned short* xv  = (unsigned short*)(ws + 3244032);
    unsigned short* qh  = (unsigned short*)(ws + 5832704);
    unsigned short* kh  = (unsigned short*)(ws + 6488064);
    unsigned short* vhT = (unsigned short*)(ws + 9076736);    // [128][10112] bf16, pair-permuted
    unsigned short* wqT = (unsigned short*)(ws + 11665408);
    unsigned short* wkT = (unsigned short*)(ws + 11698176);
    unsigned short* wvT = (unsigned short*)(ws + 11730944);
    unsigned short* wpT = (unsigned short*)(ws + 11763712);
    unsigned short* w1T = (unsigned short*)(ws + 11796480);
    unsigned short* w2T = (unsigned short*)(ws + 11862016);
    unsigned* OpartU    = (unsigned*)(ws + 11927552);         // 35*OPS u32 (padded stride)
    float* lpart        = (float*)(ws + 34876352);            // 35*LPS f32 (padded stride)
    float* linv         = (float*)(ws + 36319472);            // 2560*4 f32
    unsigned* A1u       = (unsigned*)(ws + 655360);           // overlays dead xk (2560*64 u32)
    // high-water: 36360432 bytes

    wcvt_kernel<<<dim3(512), dim3(256), 0, stream>>>(wq, wk, wv, wp, w1, w2,
                                                     wqT, wkT, wvT, wpT, w1T, w2T);
    ln_kernel<<<dim3(1417), dim3(256), 0, stream>>>(q, k, v, qn_w, qn_b, kn_w, kn_b, vn_w, vn_b,
                                                    xq, xk, xv);
    proj_kernel<<<dim3(356), dim3(256), 0, stream>>>(xq, xk, xv, wqT, wkT, wvT, bq, bk, bv,
                                                     qh, kh, vhT);
    attn_kernel<<<dim3(40 * SPLITS), dim3(256), 0, stream>>>(qh, kh, vhT, Wl, vis, OpartU, lpart);
    linv_kernel<<<dim3(40), dim3(256), 0, stream>>>(lpart, linv);
    combine_kernel<<<dim3(160), dim3(256), 0, stream>>>(OpartU, linv, A1u);
    mlp_kernel<<<dim3(40), dim3(256), 0, stream>>>((const unsigned short*)A1u, wpT, bp, skip,
                                                   pre_w, pre_b, w1T, b1, w2T, b2,
                                                   post_w, post_b, out);
}